// Round 1
// baseline (437.022 us; speedup 1.0000x reference)
//
#include <hip/hip_runtime.h>
#include <hip/hip_bf16.h>

#define T_STEPS 256
#define BATCH   2048
#define INSZ    65
#define HID     64
#define ROWS    16      // batch rows per block
#define KPAD    168     // LDS row stride (bf16 elems): x 0..64 | zero 65..95 | h 96..159 | pad
#define OUTSZ   7

typedef __attribute__((ext_vector_type(8))) short bf16x8;  // 8 bf16 in 4 VGPRs
typedef __attribute__((ext_vector_type(4))) float f32x4;

__device__ __forceinline__ short f2bf(float f) {
    union { float f; unsigned u; } v; v.f = f;
    unsigned r = (v.u + 0x7FFFu + ((v.u >> 16) & 1u)) >> 16;  // RNE
    return (short)r;
}
__device__ __forceinline__ float bf2f(short s) {
    union { unsigned u; float f; } v;
    v.u = ((unsigned)(unsigned short)s) << 16;
    return v.f;
}
__device__ __forceinline__ float sigm(float x) {
    return 1.0f / (1.0f + __expf(-x));       // x<<0: exp->inf -> 0; x>>0 -> 1
}
__device__ __forceinline__ float tanh_f(float x) {
    return 1.0f - 2.0f / (__expf(2.0f * x) + 1.0f);  // saturates correctly at +-1
}

__global__ __launch_bounds__(256)
void lstm_fused(const float* __restrict__ x,    const float* __restrict__ W_ih,
                const float* __restrict__ W_hh, const float* __restrict__ b_ih,
                const float* __restrict__ b_hh, const float* __restrict__ fc_W,
                const float* __restrict__ fc_b, float* __restrict__ out)
{
    __shared__ __align__(16) short Abuf[ROWS * KPAD];

    const int tid  = threadIdx.x;
    const int w    = tid >> 6;        // wave id 0..3
    const int lane = tid & 63;
    const int quad = lane >> 4;
    const int col  = lane & 15;
    const int b0   = blockIdx.x * ROWS;

    // zero whole LDS tile once: establishes K-padding zeros and h0 = 0
    for (int i = tid; i < ROWS * KPAD; i += 256) Abuf[i] = 0;

    // ---- W fragments (B-operand layout: n = lane&15, k = quad*8+j), resident in VGPRs ----
    const int n_lo = w * 16 + col;           // column within a gate (0..63)
    bf16x8 wfrag[4][5];
    #pragma unroll
    for (int gt = 0; gt < 4; ++gt) {
        const int n = gt * 64 + n_lo;        // row of W (gate-major, 0..255)
        #pragma unroll
        for (int kc = 0; kc < 5; ++kc) {
            bf16x8 f;
            #pragma unroll
            for (int j = 0; j < 8; ++j) {
                const int k = kc * 32 + quad * 8 + j;
                float v;
                if (k < INSZ)      v = W_ih[n * INSZ + k];
                else if (k < 96)   v = 0.0f;                  // K padding
                else               v = W_hh[n * HID + (k - 96)];
                f[j] = f2bf(v);
            }
            wfrag[gt][kc] = f;
        }
    }
    float bias[4];
    #pragma unroll
    for (int gt = 0; gt < 4; ++gt)
        bias[gt] = b_ih[gt * 64 + n_lo] + b_hh[gt * 64 + n_lo];

    // ---- x staging descriptors: 16 rows x 65 cols = 1040 elems over 256 threads ----
    int xm[5], xk[5]; bool xv[5]; const float* xp[5]; float xr[5];
    #pragma unroll
    for (int i = 0; i < 5; ++i) {
        const int idx = tid + 256 * i;
        xv[i] = (idx < ROWS * INSZ);
        const int m = idx / INSZ;
        const int k = idx - m * INSZ;
        xm[i] = m; xk[i] = k;
        xp[i] = x + (size_t)(b0 + m) * T_STEPS * INSZ + k;
        xr[i] = xv[i] ? xp[i][0] : 0.0f;     // prefetch t=0
    }

    float c[4] = {0.f, 0.f, 0.f, 0.f};
    __syncthreads();

    for (int t = 0; t < T_STEPS; ++t) {
        // stage x_t (prefetched last iter) into LDS; then kick off t+1 loads
        #pragma unroll
        for (int i = 0; i < 5; ++i)
            if (xv[i]) Abuf[xm[i] * KPAD + xk[i]] = f2bf(xr[i]);
        const int tn = (t < T_STEPS - 1) ? t + 1 : t;
        #pragma unroll
        for (int i = 0; i < 5; ++i)
            if (xv[i]) xr[i] = xp[i][tn * INSZ];
        __syncthreads();   // staging + previous h-writes visible

        // A fragments (m = lane&15, k = kc*32 + quad*8 + j) -> ds_read_b128
        bf16x8 afrag[5];
        #pragma unroll
        for (int kc = 0; kc < 5; ++kc)
            afrag[kc] = *(const bf16x8*)&Abuf[col * KPAD + kc * 32 + quad * 8];

        // gates = bias + [x_t | h] @ [W_ih | W_hh]^T   (wave w covers j in [16w,16w+16))
        f32x4 acc[4];
        #pragma unroll
        for (int gt = 0; gt < 4; ++gt) {
            f32x4 a = {bias[gt], bias[gt], bias[gt], bias[gt]};
            #pragma unroll
            for (int kc = 0; kc < 5; ++kc)
                a = __builtin_amdgcn_mfma_f32_16x16x32_bf16(afrag[kc], wfrag[gt][kc], a, 0, 0, 0);
            acc[gt] = a;
        }

        // lane l, reg r owns (row m = quad*4+r, col j = w*16+col) for ALL four gates
        short hv[4];
        #pragma unroll
        for (int r = 0; r < 4; ++r) {
            const float ig = sigm(acc[0][r]);
            const float fg = sigm(acc[1][r]);
            const float gg = tanh_f(acc[2][r]);
            const float og = sigm(acc[3][r]);
            const float cn = fg * c[r] + ig * gg;
            c[r] = cn;
            hv[r] = f2bf(og * tanh_f(cn));
        }
        __syncthreads();   // all A-fragment reads done before h/x overwrite
        #pragma unroll
        for (int r = 0; r < 4; ++r)
            Abuf[(quad * 4 + r) * KPAD + 96 + w * 16 + col] = hv[r];
    }
    __syncthreads();

    // ---- FC(64->7) + sigmoid on final h (bf16 in LDS h-region) ----
    if (tid < ROWS * OUTSZ) {
        const int m = tid & 15;
        const int o = tid >> 4;
        float s = fc_b[o];
        #pragma unroll
        for (int k = 0; k < HID; ++k)
            s += bf2f(Abuf[m * KPAD + 96 + k]) * fc_W[o * HID + k];
        out[(size_t)(b0 + m) * OUTSZ + o] = sigm(s);
    }
}

extern "C" void kernel_launch(void* const* d_in, const int* in_sizes, int n_in,
                              void* d_out, int out_size, void* d_ws, size_t ws_size,
                              hipStream_t stream) {
    const float* x    = (const float*)d_in[0];
    const float* W_ih = (const float*)d_in[1];
    const float* W_hh = (const float*)d_in[2];
    const float* b_ih = (const float*)d_in[3];
    const float* b_hh = (const float*)d_in[4];
    const float* fc_W = (const float*)d_in[5];
    const float* fc_b = (const float*)d_in[6];
    float* out = (float*)d_out;

    dim3 grid(BATCH / ROWS);   // 128 blocks, each owns 16 batch rows for all 256 steps
    dim3 block(256);           // 4 waves
    hipLaunchKernelGGL(lstm_fused, grid, block, 0, stream,
                       x, W_ih, W_hh, b_ih, b_hh, fc_W, fc_b, out);
}

// Round 2
// 352.808 us; speedup vs baseline: 1.2387x; 1.2387x over previous
//
#include <hip/hip_runtime.h>
#include <hip/hip_bf16.h>

#define T_STEPS 256
#define BATCH   2048
#define INSZ    65
#define HID     64
#define ROWS    4       // batch rows per block -> 512 blocks = 2 blocks/CU
#define KPAD    168     // LDS A row stride (bf16): x 0..64 | zero 65..95 | h 96..159 | pad
#define GPAD    20      // gate buffer stride per column j (f32 words, 16B-aligned, stride 20 banks)
#define OUTSZ   7
#define NTHREADS 512

typedef __attribute__((ext_vector_type(8))) short bf16x8;  // 8 bf16 in 4 VGPRs
typedef __attribute__((ext_vector_type(4))) float f32x4;

__device__ __forceinline__ short f2bf(float f) {
    union { float f; unsigned u; } v; v.f = f;
    unsigned r = (v.u + 0x7FFFu + ((v.u >> 16) & 1u)) >> 16;  // RNE
    return (short)r;
}
__device__ __forceinline__ float bf2f(short s) {
    union { unsigned u; float f; } v;
    v.u = ((unsigned)(unsigned short)s) << 16;
    return v.f;
}
__device__ __forceinline__ float sigm(float x) {
    return 1.0f / (1.0f + __expf(-x));
}
__device__ __forceinline__ float tanh_f(float x) {
    return 1.0f - 2.0f / (__expf(2.0f * x) + 1.0f);
}

__global__ __launch_bounds__(NTHREADS, 4)   // 4 waves/EU -> 16 waves/CU -> 2 blocks/CU
void lstm_fused(const float* __restrict__ x,    const float* __restrict__ W_ih,
                const float* __restrict__ W_hh, const float* __restrict__ b_ih,
                const float* __restrict__ b_hh, const float* __restrict__ fc_W,
                const float* __restrict__ fc_b, float* __restrict__ out)
{
    __shared__ __align__(16) short Abuf[16 * KPAD];      // rows 0..3 real, 4..15 stay zero
    __shared__ __align__(16) float gbuf[64 * GPAD];      // [j][m*4+gate], padded

    const int tid  = threadIdx.x;
    const int w    = tid >> 6;        // wave 0..7
    const int lane = tid & 63;
    const int quad = lane >> 4;
    const int col  = lane & 15;
    const int b0   = blockIdx.x * ROWS;

    // zero A tile once: K-padding zeros, garbage rows zero, h0 = 0
    for (int i = tid; i < 16 * KPAD; i += NTHREADS) Abuf[i] = 0;

    // ---- W fragments: wave w owns tiles tt = 2w, 2w+1 over [gate][ntile] grid ----
    // B-operand layout: n = lane&15, k = quad*8 + j
    bf16x8 wfrag[2][5];
    float  bias[2];
    int    tgt[2], tnt[2];
    #pragma unroll
    for (int tle = 0; tle < 2; ++tle) {
        const int tt = w * 2 + tle;
        const int gt = tt >> 2, nt = tt & 3;
        tgt[tle] = gt; tnt[tle] = nt;
        const int n = gt * 64 + nt * 16 + col;    // row of W (gate-major)
        #pragma unroll
        for (int kc = 0; kc < 5; ++kc) {
            bf16x8 f;
            #pragma unroll
            for (int j = 0; j < 8; ++j) {
                const int k = kc * 32 + quad * 8 + j;
                float v;
                if (k < INSZ)      v = W_ih[n * INSZ + k];
                else if (k < 96)   v = 0.0f;
                else               v = W_hh[n * HID + (k - 96)];
                f[j] = f2bf(v);
            }
            wfrag[tle][kc] = f;
        }
        bias[tle] = b_ih[n] + b_hh[n];
    }

    // ---- x staging: 4 rows x 65 = 260 elements, one per thread ----
    const bool xa = (tid < ROWS * INSZ);
    const int  xm = tid / INSZ;
    const int  xk = tid - xm * INSZ;
    const float* xq = x + (size_t)(b0 + xm) * T_STEPS * INSZ + xk;
    float xr = xa ? *xq : 0.0f;            // t = 0
    xq += INSZ;                            // -> t = 1

    // ---- activation lane assignment: pair p = tid < 256 -> (m = p&3, j = p>>2) ----
    const bool rd = (tid < ROWS * HID);
    const int  rm = tid & 3;
    const int  rj = tid >> 2;
    float c = 0.0f;

    __syncthreads();

    for (int t = 0; t < T_STEPS; ++t) {
        // stage x_t (prefetched), kick off x_{t+1}
        if (xa) Abuf[xm * KPAD + xk] = f2bf(xr);
        if (xa) xr = *xq;
        if (t < T_STEPS - 2) xq += INSZ;
        __syncthreads();                           // x + h visible

        // A fragments (m = lane&15, k = kc*32 + quad*8 + j); shared by both tiles
        bf16x8 afrag[5];
        #pragma unroll
        for (int kc = 0; kc < 5; ++kc)
            afrag[kc] = *(const bf16x8*)&Abuf[col * KPAD + kc * 32 + quad * 8];

        f32x4 acc[2];
        #pragma unroll
        for (int tle = 0; tle < 2; ++tle) {
            f32x4 a = {bias[tle], bias[tle], bias[tle], bias[tle]};
            #pragma unroll
            for (int kc = 0; kc < 5; ++kc)
                a = __builtin_amdgcn_mfma_f32_16x16x32_bf16(afrag[kc], wfrag[tle][kc], a, 0, 0, 0);
            acc[tle] = a;
        }

        // C-layout: row m = quad*4 + r, col j = nt*16 + col. Only m<4 real -> quad 0.
        if (quad == 0) {
            #pragma unroll
            for (int tle = 0; tle < 2; ++tle) {
                const int j = tnt[tle] * 16 + col;
                #pragma unroll
                for (int r = 0; r < 4; ++r)
                    gbuf[j * GPAD + r * 4 + tgt[tle]] = acc[tle][r];
            }
        }
        __syncthreads();                           // gates visible

        if (rd) {
            const f32x4 g4 = *(const f32x4*)&gbuf[rj * GPAD + rm * 4];  // i,f,g,o
            const float ig = sigm(g4[0]);
            const float fg = sigm(g4[1]);
            const float gg = tanh_f(g4[2]);
            const float og = sigm(g4[3]);
            c = fg * c + ig * gg;
            Abuf[rm * KPAD + 96 + rj] = f2bf(og * tanh_f(c));
        }
    }
    __syncthreads();

    // ---- FC(64->7) + sigmoid on final h ----
    if (tid < ROWS * OUTSZ) {
        const int m = tid & 3;
        const int o = tid >> 2;
        float s = fc_b[o];
        #pragma unroll
        for (int k = 0; k < HID; ++k)
            s += bf2f(Abuf[m * KPAD + 96 + k]) * fc_W[o * HID + k];
        out[(size_t)(b0 + m) * OUTSZ + o] = sigm(s);
    }
}

extern "C" void kernel_launch(void* const* d_in, const int* in_sizes, int n_in,
                              void* d_out, int out_size, void* d_ws, size_t ws_size,
                              hipStream_t stream) {
    const float* x    = (const float*)d_in[0];
    const float* W_ih = (const float*)d_in[1];
    const float* W_hh = (const float*)d_in[2];
    const float* b_ih = (const float*)d_in[3];
    const float* b_hh = (const float*)d_in[4];
    const float* fc_W = (const float*)d_in[5];
    const float* fc_b = (const float*)d_in[6];
    float* out = (float*)d_out;

    dim3 grid(BATCH / ROWS);   // 512 blocks -> 2 per CU
    dim3 block(NTHREADS);      // 8 waves
    hipLaunchKernelGGL(lstm_fused, grid, block, 0, stream,
                       x, W_ih, W_hh, b_ih, b_hh, fc_W, fc_b, out);
}